// Round 1
// 426.376 us; speedup vs baseline: 1.0502x; 1.0502x over previous
//
#include <hip/hip_runtime.h>
#include <math.h>

#define Hn 128
#define Wn 256
#define PLANE (Hn*Wn)

// Workspace layout (float offsets)
#define OFF_TQC 0u        // [j<32][xi<16] float4: cos(2pi*j*(xi*4+m)/256), x<64 quarter
#define OFF_TQS 2048u     // sin
#define OFF_TP  4096u     // [p<32][y2<64] float4: (c,s) at y=2y2 and y=2y2+1, theta=2pi*p*y/128
#define OFF_KM  16384u    // [c=32][mode=2048] float2 (plane-major spectrum of k)
#define OFF_XM  147456u   // [plane=1024][mode=2048] float2
#define OFF_B   4341760u  // time-shared: R [1024][128][32] f2 -> WK [mode][c][o] f2 -> G' [1024][128][32] f2
#define OFF_RK  12730368u // Rk [32][128][32] float2
// total 12992512 floats = 49.6 MiB

__global__ __launch_bounds__(256) void build_tables(float* __restrict__ ws) {
  int tid = blockIdx.x * 256 + threadIdx.x; // 2048 threads
  const double PI2 = 6.283185307179586476925286766559;
  if (tid < 512) {
    int j = tid >> 4, xi = tid & 15;
    float cc[4], ss[4];
#pragma unroll
    for (int m = 0; m < 4; m++) {
      int x = xi * 4 + m;
      double ang = PI2 * (double)((j * x) & 255) / 256.0;
      cc[m] = (float)cos(ang); ss[m] = (float)sin(ang);
    }
    ((float4*)(ws + OFF_TQC))[tid] = make_float4(cc[0], cc[1], cc[2], cc[3]);
    ((float4*)(ws + OFF_TQS))[tid] = make_float4(ss[0], ss[1], ss[2], ss[3]);
  }
  if (tid < 2048) {
    int p = tid >> 6, y2 = tid & 63;
    double a0 = PI2 * (double)((p * (2 * y2)) & 127) / 128.0;
    double a1 = PI2 * (double)((p * (2 * y2 + 1)) & 127) / 128.0;
    ((float4*)(ws + OFF_TP))[tid] =
        make_float4((float)cos(a0), (float)sin(a0), (float)cos(a1), (float)sin(a1));
  }
}

// x-DFT with even/odd fold: R[plane][y][j] = sum_x u[y,x] e^{-2pi i j x/256}, j<32.
// Fold x <-> 256-x (u real): Re = sum_{x<128} E[x] c[jx] + u128*(-1)^j,
//                            Im = -sum_{x<128} O[x] s[jx].
// E/O built in place in the staged LDS tile; quarter table serves both 64-halves
// via the theta+pi*j/2 rotation (table-pointer swap per j, sign in epilogue).
__global__ __launch_bounds__(256, 3) void fwd_rows(const float* __restrict__ src,
                                                   float2* __restrict__ R,
                                                   const float* __restrict__ ws) {
  int plane = blockIdx.x >> 2, chunk = blockIdx.x & 3;
  // Data tile: 32 rows x 260 floats. After fold:
  //   slots [0..127]=E, slot 128=u[128], slots [129..255]=O[1..127], rest pad.
  // 16B-chunk XOR swizzle (chunk c -> c ^ ((y>>1)&15)) spreads banks.
  __shared__ __align__(16) float Sd[32 * 260];
  __shared__ float4 Tc[544], Ts[544];  // [j][17] padded
  int t = threadIdx.x;
  const float4* src4 = (const float4*)src;
  size_t sb = (size_t)plane * 8192 + (size_t)chunk * 2048;
  // Phase 1: stage raw u tile (swizzled chunks).
#pragma unroll
  for (int k = 0; k < 8; k++) {
    int idx = t + 256 * k;           // 2048 float4 = 32 y x 64 chunks
    int row = idx >> 6, c4 = idx & 63;
    int sws = (row >> 1) & 15;
    *(float4*)&Sd[row * 260 + ((c4 ^ sws) << 2)] = src4[sb + idx];
  }
  const float4* gTc = (const float4*)(ws + OFF_TQC);
  const float4* gTs = (const float4*)(ws + OFF_TQS);
#pragma unroll
  for (int k = 0; k < 2; k++) {
    int idx = t + 256 * k;
    Tc[(idx >> 4) * 17 + (idx & 15)] = gTc[idx];
    Ts[(idx >> 4) * 17 + (idx & 15)] = gTs[idx];
  }
  __syncthreads();
  // Phase 2a: compute E/O into registers. 1024 units = (y<32, xb<32), 4/thread.
  float eA[4][4], oA[4][4];
#pragma unroll
  for (int uu = 0; uu < 4; uu++) {
    int unit = uu * 256 + t;
    int y = unit >> 5, xb = unit & 31;
    int sws = (y >> 1) & 15;
    const float* rowp = &Sd[y * 260];
    float4 A = *(const float4*)&rowp[(xb ^ sws) << 2];
    float Av[4] = {A.x, A.y, A.z, A.w};
    float M[4];
#pragma unroll
    for (int kk = 0; kk < 4; kk++) {
      int xm = 256 - 4 * xb - kk;            // mirror index in [129..256]
      int xmc = (xm > 255) ? 255 : xm;       // clamp (only xb==0,kk==0 hits 256)
      int c4m = xmc >> 2, e = xmc & 3;
      float v = rowp[((c4m ^ sws) << 2) + e];
      M[kk] = (xm > 255) ? 0.f : v;
    }
#pragma unroll
    for (int kk = 0; kk < 4; kk++) {
      eA[uu][kk] = Av[kk] + M[kk];
      oA[uu][kk] = Av[kk] - M[kk];
    }
    if (xb == 0) {
      // O-slot 128 must keep u[128] (read back in epilogue; killed by s[j][0]=0 in dots).
      oA[uu][0] = rowp[(32 ^ sws) << 2];
    }
  }
  __syncthreads();
  // Phase 2b: write E (chunks 0..31) and O (chunks 32..63), same swizzle.
#pragma unroll
  for (int uu = 0; uu < 4; uu++) {
    int unit = uu * 256 + t;
    int y = unit >> 5, xb = unit & 31;
    int sws = (y >> 1) & 15;
    float* rowp = &Sd[y * 260];
    *(float4*)&rowp[(xb ^ sws) << 2] =
        make_float4(eA[uu][0], eA[uu][1], eA[uu][2], eA[uu][3]);
    *(float4*)&rowp[((32 + xb) ^ sws) << 2] =
        make_float4(oA[uu][0], oA[uu][1], oA[uu][2], oA[uu][3]);
  }
  __syncthreads();
  // Main loop: 2 j (jg, jg+16) x 2 y per thread; 4 real dots each.
  int jg = t & 15, yg = t >> 4;
  int jm = jg & 3;                    // same for jg and jg+16
  const float4* pC0 = &Tc[jg * 17];
  const float4* pS0 = &Ts[jg * 17];
  const float4* pC1 = &Tc[(jg + 16) * 17];
  const float4* pS1 = &Ts[(jg + 16) * 17];
  // E1 half uses cos(theta+pi*j/2): jm 0:+C 1:-S 2:-C 3:+S
  // O1 half uses sin(theta+pi*j/2): jm 0:+S 1:+C 2:-S 3:-C
  const float4* p2_0 = (jm & 1) ? pS0 : pC0;
  const float4* p4_0 = (jm & 1) ? pC0 : pS0;
  const float4* p2_1 = (jm & 1) ? pS1 : pC1;
  const float4* p4_1 = (jm & 1) ? pC1 : pS1;
  float sa = (jm == 0 || jm == 3) ? 1.f : -1.f;
  float sb_ = (jm < 2) ? 1.f : -1.f;
  float pm = (jg & 1) ? -1.f : 1.f;   // (-1)^j, same parity for jg and jg+16
  int sw = yg & 15;                   // (y>>1)&15 for y=2yg, 2yg+1
  const float* row0 = &Sd[(2 * yg) * 260];
  const float* row1 = &Sd[(2 * yg + 1) * 260];
  float d1[2][2], d2[2][2], d3[2][2], d4[2][2];
#pragma unroll
  for (int a = 0; a < 2; a++)
#pragma unroll
    for (int b = 0; b < 2; b++) { d1[a][b] = 0.f; d2[a][b] = 0.f; d3[a][b] = 0.f; d4[a][b] = 0.f; }
#define DOT4(a, b) (a.x * b.x + a.y * b.y + a.z * b.z + a.w * b.w)
#pragma unroll 4
  for (int xb = 0; xb < 16; xb++) {
    int off = (xb ^ sw) << 2;
    float4 e0y0 = *(const float4*)&row0[off];
    float4 e1y0 = *(const float4*)&row0[off + 64];
    float4 o0y0 = *(const float4*)&row0[off + 128];
    float4 o1y0 = *(const float4*)&row0[off + 192];
    float4 e0y1 = *(const float4*)&row1[off];
    float4 e1y1 = *(const float4*)&row1[off + 64];
    float4 o0y1 = *(const float4*)&row1[off + 128];
    float4 o1y1 = *(const float4*)&row1[off + 192];
    float4 c0 = pC0[xb], s0 = pS0[xb];
    float4 t20 = p2_0[xb], t40 = p4_0[xb];
    float4 c1 = pC1[xb], s1 = pS1[xb];
    float4 t21 = p2_1[xb], t41 = p4_1[xb];
    d1[0][0] += DOT4(e0y0, c0);  d1[0][1] += DOT4(e0y1, c0);
    d1[1][0] += DOT4(e0y0, c1);  d1[1][1] += DOT4(e0y1, c1);
    d2[0][0] += DOT4(e1y0, t20); d2[0][1] += DOT4(e1y1, t20);
    d2[1][0] += DOT4(e1y0, t21); d2[1][1] += DOT4(e1y1, t21);
    d3[0][0] += DOT4(o0y0, s0);  d3[0][1] += DOT4(o0y1, s0);
    d3[1][0] += DOT4(o0y0, s1);  d3[1][1] += DOT4(o0y1, s1);
    d4[0][0] += DOT4(o1y0, t40); d4[0][1] += DOT4(o1y1, t40);
    d4[1][0] += DOT4(o1y0, t41); d4[1][1] += DOT4(o1y1, t41);
  }
#undef DOT4
  float u128_0 = row0[128 + 4 * sw];  // slot 128 (chunk 32^sw, elem 0)
  float u128_1 = row1[128 + 4 * sw];
#pragma unroll
  for (int jj = 0; jj < 2; jj++) {
    int j = jg + 16 * jj;
#pragma unroll
    for (int ky = 0; ky < 2; ky++) {
      int y = chunk * 32 + yg * 2 + ky;
      float u128 = ky ? u128_1 : u128_0;
      float re = d1[jj][ky] + sa * d2[jj][ky] + pm * u128;
      float im = -(d3[jj][ky] + sb_ * d4[jj][ky]);
      R[((size_t)plane * 128 + y) * 32 + j] = make_float2(re, im);
    }
  }
}

// y-DFT with row pairing (r, r+96): factor i^y. Output plane-major dst[plane][i64*32+j].
__global__ __launch_bounds__(256) void fwd_cols(const float2* __restrict__ Rg,
                                                float2* __restrict__ dst,
                                                const float* __restrict__ ws) {
  int plane = blockIdx.x;
  __shared__ float4 Rs4[2048];   // [y=128][j=32] float2 = 2048 float4 (32 KB)
  __shared__ float4 TPs[2048];   // [p][y2] (32 KB)
  float2* Rs = (float2*)Rs4;
  int t = threadIdx.x;
  const float4* in4 = (const float4*)(Rg + (size_t)plane * 4096);
#pragma unroll
  for (int k = 0; k < 8; k++) Rs4[t + 256 * k] = in4[t + 256 * k];
  const float4* gTP = (const float4*)(ws + OFF_TP);
#pragma unroll
  for (int k = 0; k < 8; k++) TPs[t + 256 * k] = gTP[t + 256 * k];
  __syncthreads();
  int j = t & 31, pg = t >> 5;
  float Are[4], Aim[4], Bre[4], Bim[4];
#pragma unroll
  for (int m = 0; m < 4; m++) { Are[m] = Aim[m] = Bre[m] = Bim[m] = 0.f; }
  for (int it = 0; it < 32; it++) {
#pragma unroll
    for (int h = 0; h < 2; h++) {
      int y2 = 2 * it + h;
      float sg = (h == 0) ? 1.f : -1.f;  // (-1)^y2
      float2 r0 = Rs[(2 * y2) * 32 + j];
      float2 r1 = Rs[(2 * y2 + 1) * 32 + j];
#pragma unroll
      for (int m = 0; m < 4; m++) {
        int p = pg + 8 * m;
        float4 tw = TPs[p * 64 + y2];
        float P0 = r0.x * tw.x + r0.y * tw.y;
        float Q0 = r0.y * tw.x - r0.x * tw.y;
        float P1 = r1.x * tw.z + r1.y * tw.w;
        float Q1 = r1.y * tw.z - r1.x * tw.w;
        Are[m] += P0 + P1;
        Aim[m] += Q0 + Q1;
        Bre[m] += sg * (P0 - Q1);   // i^y fold: even +sg*(P,Q); odd +sg*(-Q,P)
        Bim[m] += sg * (Q0 + P1);
      }
    }
  }
  size_t ob = (size_t)plane * 2048;
#pragma unroll
  for (int m = 0; m < 4; m++) {
    int p = pg + 8 * m;
    dst[ob + p * 32 + j] = make_float2(Are[m], Aim[m]);
    dst[ob + (32 + p) * 32 + j] = make_float2(Bre[m], Bim[m]);
  }
}

// Wk[mode][c][o] = Km[c][mode] * (w1|w2)[c][o][r][j]
__global__ __launch_bounds__(256) void wk_build(const float* __restrict__ w1r,
                                                const float* __restrict__ w1i,
                                                const float* __restrict__ w2r,
                                                const float* __restrict__ w2i,
                                                float2* __restrict__ wk,
                                                const float2* __restrict__ km) {
  int e0 = blockIdx.x * 256 + threadIdx.x;
#pragma unroll
  for (int k = 0; k < 4; k++) {
    int e = e0 + k * 524288;
    int o = e & 31, c = (e >> 5) & 31, j = (e >> 10) & 31, i64 = e >> 15;
    int r = (i64 < 32) ? i64 : i64 - 32;
    const float* wr = (i64 < 32) ? w1r : w2r;
    const float* wi = (i64 < 32) ? w1i : w2i;
    int widx = ((c * 32 + o) * 32 + r) * 32 + j;
    float wrv = wr[widx], wiv = wi[widx];
    float2 kv = km[(size_t)c * 2048 + i64 * 32 + j];
    wk[e] = make_float2(kv.x * wrv - kv.y * wiv, kv.x * wiv + kv.y * wrv);
  }
}

// Per-mode channel mixing on plane-major xm; XCD-swizzled gather/scatter.
__global__ __launch_bounds__(256) void mix_modes(float2* __restrict__ xm,
                                                 const float2* __restrict__ wk) {
  int bid = blockIdx.x;
  int mode = (bid & 7) * 256 + (bid >> 3);
  __shared__ float4 Xs4[512], Ws4[512];
  float2* Xs = (float2*)Xs4;
  float2* Wsl = (float2*)Ws4;
  int t = threadIdx.x;
#pragma unroll
  for (int k = 0; k < 4; k++) {
    int p = t + 256 * k;
    Xs[p] = xm[(size_t)p * 2048 + mode];
  }
  const float4* wk4 = (const float4*)(wk + (size_t)mode * 1024);
#pragma unroll
  for (int k = 0; k < 2; k++) Ws4[t + 256 * k] = wk4[t + 256 * k];
  __syncthreads();
  int o = t & 31, bg = t >> 5;
  float orr[4], oii[4];
#pragma unroll
  for (int m = 0; m < 4; m++) { orr[m] = 0.f; oii[m] = 0.f; }
  for (int c2 = 0; c2 < 16; c2++) {
    float2 w0 = Wsl[(2 * c2) * 32 + o];
    float2 w1 = Wsl[(2 * c2 + 1) * 32 + o];
#pragma unroll
    for (int m = 0; m < 4; m++) {
      float4 xv = *(const float4*)&Xs[(bg * 4 + m) * 32 + 2 * c2];
      orr[m] += xv.x * w0.x - xv.y * w0.y + xv.z * w1.x - xv.w * w1.y;
      oii[m] += xv.x * w0.y + xv.y * w0.x + xv.z * w1.y + xv.w * w1.x;
    }
  }
#pragma unroll
  for (int m = 0; m < 4; m++)
    xm[(size_t)((bg * 4 + m) * 32 + o) * 2048 + mode] = make_float2(orr[m], oii[m]);
}

// Inverse y-DFT with pairing: G[y] = sum_p (A_p + (-i)^y B_p) e^{+i theta_py}; scaling folded.
__global__ __launch_bounds__(256) void inv_rows(const float2* __restrict__ om,
                                                float2* __restrict__ G,
                                                const float* __restrict__ ws) {
  int plane = blockIdx.x;
  __shared__ float4 Os4[1024];   // [i64][j] float2 (2048 float2)
  __shared__ float4 TPs[2048];
  float2* Os = (float2*)Os4;
  int t = threadIdx.x;
  const float4* in4 = (const float4*)(om + (size_t)plane * 2048);
#pragma unroll
  for (int k = 0; k < 4; k++) Os4[t + 256 * k] = in4[t + 256 * k];
  const float4* gTP = (const float4*)(ws + OFF_TP);
#pragma unroll
  for (int k = 0; k < 8; k++) TPs[t + 256 * k] = gTP[t + 256 * k];
  __syncthreads();
  int j = t & 31, yg = t >> 5;
  float gr[16], gi[16];
#pragma unroll
  for (int k = 0; k < 16; k++) { gr[k] = 0.f; gi[k] = 0.f; }
  for (int p = 0; p < 32; p++) {
    float2 A = Os[p * 32 + j];
    float2 B = Os[(32 + p) * 32 + j];
#pragma unroll
    for (int mp = 0; mp < 8; mp++) {
      int y2 = yg * 8 + mp;
      float4 tw = TPs[p * 64 + y2];
      float sg = ((mp & 1) == 0) ? 1.f : -1.f;  // (-1)^y2
      float Sr = A.x + sg * B.x, Si = A.y + sg * B.y;          // y even
      gr[2 * mp]     += Sr * tw.x - Si * tw.y;
      gi[2 * mp]     += Sr * tw.y + Si * tw.x;
      float Tr = A.x + sg * B.y, Ti = A.y - sg * B.x;          // y odd: +sg*(-i)B
      gr[2 * mp + 1] += Tr * tw.z - Ti * tw.w;
      gi[2 * mp + 1] += Tr * tw.w + Ti * tw.z;
    }
  }
  const float inv = 1.0f / 32768.0f;
  size_t gb = (size_t)plane * 128;
#pragma unroll
  for (int mm = 0; mm < 16; mm++) {
    int y = yg * 16 + mm;
    float sr = (j == 0) ? gr[mm] * inv : 2.f * inv * gr[mm];
    float si = (j == 0) ? 0.f : 2.f * inv * gi[mm];
    G[(gb + y) * 32 + j] = make_float2(sr, si);
  }
}

// Inverse x-DFT: out[y][x] = sum_jj Re(G[y][jj] e^{+2pi i jj x/256}); quarter-folded twiddles.
__global__ __launch_bounds__(256) void inv_cols(const float2* __restrict__ G,
                                                float* __restrict__ out,
                                                const float* __restrict__ ws) {
  int plane = blockIdx.x >> 2, chunk = blockIdx.x & 3;
  __shared__ float2 Gs[32 * 33];       // padded [yl][33]
  __shared__ float4 Tc[544], Ts[544];  // [jj][17] padded
  int t = threadIdx.x;
  const float2* in = G + (size_t)plane * 4096 + (size_t)chunk * 1024;
#pragma unroll
  for (int k = 0; k < 4; k++) {
    int idx = t + 256 * k;
    Gs[(idx >> 5) * 33 + (idx & 31)] = in[idx];
  }
  const float4* gTc = (const float4*)(ws + OFF_TQC);
  const float4* gTs = (const float4*)(ws + OFF_TQS);
#pragma unroll
  for (int k = 0; k < 2; k++) {
    int idx = t + 256 * k;
    Tc[(idx >> 4) * 17 + (idx & 15)] = gTc[idx];
    Ts[(idx >> 4) * 17 + (idx & 15)] = gTs[idx];
  }
  __syncthreads();
  int xi = t & 15, yg = t >> 4;
  float4 acc[2][4];
#pragma unroll
  for (int ky = 0; ky < 2; ky++)
#pragma unroll
    for (int q = 0; q < 4; q++) acc[ky][q] = make_float4(0.f, 0.f, 0.f, 0.f);
  for (int jjb = 0; jjb < 8; jjb++) {
#pragma unroll
    for (int jjo = 0; jjo < 4; jjo++) {
      int jj = jjb * 4 + jjo;
      float4 c4 = Tc[jj * 17 + xi];
      float4 s4 = Ts[jj * 17 + xi];
#pragma unroll
      for (int ky = 0; ky < 2; ky++) {
        float2 g = Gs[(yg * 2 + ky) * 33 + jj];
        float4 P, Q;
        P.x = g.x * c4.x - g.y * s4.x;  P.y = g.x * c4.y - g.y * s4.y;
        P.z = g.x * c4.z - g.y * s4.z;  P.w = g.x * c4.w - g.y * s4.w;
        Q.x = g.x * s4.x + g.y * c4.x;  Q.y = g.x * s4.y + g.y * c4.y;
        Q.z = g.x * s4.z + g.y * c4.z;  Q.w = g.x * s4.w + g.y * c4.w;
#pragma unroll
        for (int q = 0; q < 4; q++) {
          int m = (jjo * q) & 3;  // contribution of quarter q: i^(jj*q) fold
          if (m == 0) {
            acc[ky][q].x += P.x; acc[ky][q].y += P.y; acc[ky][q].z += P.z; acc[ky][q].w += P.w;
          } else if (m == 1) {
            acc[ky][q].x -= Q.x; acc[ky][q].y -= Q.y; acc[ky][q].z -= Q.z; acc[ky][q].w -= Q.w;
          } else if (m == 2) {
            acc[ky][q].x -= P.x; acc[ky][q].y -= P.y; acc[ky][q].z -= P.z; acc[ky][q].w -= P.w;
          } else {
            acc[ky][q].x += Q.x; acc[ky][q].y += Q.y; acc[ky][q].z += Q.z; acc[ky][q].w += Q.w;
          }
        }
      }
    }
  }
  float* outp = out + (size_t)plane * PLANE + (size_t)chunk * 32 * Wn;
#pragma unroll
  for (int ky = 0; ky < 2; ky++) {
    int y = yg * 2 + ky;
#pragma unroll
    for (int q = 0; q < 4; q++)
      *(float4*)(outp + y * Wn + q * 64 + xi * 4) = acc[ky][q];
  }
}

extern "C" void kernel_launch(void* const* d_in, const int* in_sizes, int n_in,
                              void* d_out, int out_size, void* d_ws, size_t ws_size,
                              hipStream_t stream) {
  (void)in_sizes; (void)n_in; (void)out_size; (void)ws_size;
  const float* x   = (const float*)d_in[0];
  const float* kk  = (const float*)d_in[1];
  const float* w1r = (const float*)d_in[2];
  const float* w1i = (const float*)d_in[3];
  const float* w2r = (const float*)d_in[4];
  const float* w2i = (const float*)d_in[5];
  float*  ws   = (float*)d_ws;
  float*  out  = (float*)d_out;
  float2* km2  = (float2*)(ws + OFF_KM);
  float2* xm2  = (float2*)(ws + OFF_XM);
  float2* bx   = (float2*)(ws + OFF_B);   // R -> WK -> G'
  float2* rk   = (float2*)(ws + OFF_RK);

  build_tables<<<8, 256, 0, stream>>>(ws);
  fwd_rows<<<4096, 256, 0, stream>>>(x, bx, ws);
  fwd_rows<<<128, 256, 0, stream>>>(kk, rk, ws);
  fwd_cols<<<1024, 256, 0, stream>>>(bx, xm2, ws);
  fwd_cols<<<32, 256, 0, stream>>>(rk, km2, ws);
  wk_build<<<2048, 256, 0, stream>>>(w1r, w1i, w2r, w2i, bx, km2);
  mix_modes<<<2048, 256, 0, stream>>>(xm2, bx);
  inv_rows<<<1024, 256, 0, stream>>>(xm2, bx, ws);
  inv_cols<<<4096, 256, 0, stream>>>(bx, out, ws);
}

// Round 2
// 425.287 us; speedup vs baseline: 1.0529x; 1.0026x over previous
//
#include <hip/hip_runtime.h>
#include <math.h>

#define Hn 128
#define Wn 256
#define PLANE (Hn*Wn)

// Workspace layout (float offsets)
#define OFF_TQC 0u        // [j<32][xi<16] float4: cos(2pi*j*(xi*4+m)/256), x<64 quarter
#define OFF_TQS 2048u     // sin
#define OFF_TP  4096u     // [p<32][y2<64] float4: (c,s) at y=2y2 and y=2y2+1, theta=2pi*p*y/128
#define OFF_KM  16384u    // [c=32][mode=2048] float2 (plane-major spectrum of k)
#define OFF_XM  147456u   // [plane=1024][mode=2048] float2
#define OFF_B   4341760u  // time-shared: R [1024][128][32] f2 -> WK [mode][c][o] f2 -> G' [1024][128][32] f2
#define OFF_RK  12730368u // Rk [32][128][32] float2
// total 12992512 floats = 49.6 MiB

__global__ __launch_bounds__(256) void build_tables(float* __restrict__ ws) {
  int tid = blockIdx.x * 256 + threadIdx.x; // 2048 threads
  const double PI2 = 6.283185307179586476925286766559;
  if (tid < 512) {
    int j = tid >> 4, xi = tid & 15;
    float cc[4], ss[4];
#pragma unroll
    for (int m = 0; m < 4; m++) {
      int x = xi * 4 + m;
      double ang = PI2 * (double)((j * x) & 255) / 256.0;
      cc[m] = (float)cos(ang); ss[m] = (float)sin(ang);
    }
    ((float4*)(ws + OFF_TQC))[tid] = make_float4(cc[0], cc[1], cc[2], cc[3]);
    ((float4*)(ws + OFF_TQS))[tid] = make_float4(ss[0], ss[1], ss[2], ss[3]);
  }
  if (tid < 2048) {
    int p = tid >> 6, y2 = tid & 63;
    double a0 = PI2 * (double)((p * (2 * y2)) & 127) / 128.0;
    double a1 = PI2 * (double)((p * (2 * y2 + 1)) & 127) / 128.0;
    ((float4*)(ws + OFF_TP))[tid] =
        make_float4((float)cos(a0), (float)sin(a0), (float)cos(a1), (float)sin(a1));
  }
}

// x-DFT with even/odd fold: R[plane][y][j] = sum_x u[y,x] e^{-2pi i j x/256}, j<32.
// Fold x <-> 256-x (u real): Re = sum_{x<128} E[x] c[jx] + u128*(-1)^j,
//                            Im = -sum_{x<128} O[x] s[jx].
// E/O built in place in the staged LDS tile; quarter table serves both 64-halves
// via the theta+pi*j/2 rotation (table-pointer swap per j, sign in epilogue).
__global__ __launch_bounds__(256, 3) void fwd_rows(const float* __restrict__ src,
                                                   float2* __restrict__ R,
                                                   const float* __restrict__ ws) {
  int plane = blockIdx.x >> 2, chunk = blockIdx.x & 3;
  // Data tile: 32 rows x 260 floats. After fold:
  //   slots [0..127]=E, slot 128=u[128], slots [129..255]=O[1..127], rest pad.
  // 16B-chunk XOR swizzle (chunk c -> c ^ ((y>>1)&15)) spreads banks.
  __shared__ __align__(16) float Sd[32 * 260];
  __shared__ float4 Tc[544], Ts[544];  // [j][17] padded
  int t = threadIdx.x;
  const float4* src4 = (const float4*)src;
  size_t sb = (size_t)plane * 8192 + (size_t)chunk * 2048;
  // Phase 1: stage raw u tile (swizzled chunks).
#pragma unroll
  for (int k = 0; k < 8; k++) {
    int idx = t + 256 * k;           // 2048 float4 = 32 y x 64 chunks
    int row = idx >> 6, c4 = idx & 63;
    int sws = (row >> 1) & 15;
    *(float4*)&Sd[row * 260 + ((c4 ^ sws) << 2)] = src4[sb + idx];
  }
  const float4* gTc = (const float4*)(ws + OFF_TQC);
  const float4* gTs = (const float4*)(ws + OFF_TQS);
#pragma unroll
  for (int k = 0; k < 2; k++) {
    int idx = t + 256 * k;
    Tc[(idx >> 4) * 17 + (idx & 15)] = gTc[idx];
    Ts[(idx >> 4) * 17 + (idx & 15)] = gTs[idx];
  }
  __syncthreads();
  // Phase 2a: compute E/O into registers. 1024 units = (y<32, xb<32), 4/thread.
  float eA[4][4], oA[4][4];
#pragma unroll
  for (int uu = 0; uu < 4; uu++) {
    int unit = uu * 256 + t;
    int y = unit >> 5, xb = unit & 31;
    int sws = (y >> 1) & 15;
    const float* rowp = &Sd[y * 260];
    float4 A = *(const float4*)&rowp[(xb ^ sws) << 2];
    float Av[4] = {A.x, A.y, A.z, A.w};
    float M[4];
#pragma unroll
    for (int kk = 0; kk < 4; kk++) {
      int xm = 256 - 4 * xb - kk;            // mirror index in [129..256]
      int xmc = (xm > 255) ? 255 : xm;       // clamp (only xb==0,kk==0 hits 256)
      int c4m = xmc >> 2, e = xmc & 3;
      float v = rowp[((c4m ^ sws) << 2) + e];
      M[kk] = (xm > 255) ? 0.f : v;
    }
#pragma unroll
    for (int kk = 0; kk < 4; kk++) {
      eA[uu][kk] = Av[kk] + M[kk];
      oA[uu][kk] = Av[kk] - M[kk];
    }
    if (xb == 0) {
      // O-slot 128 must keep u[128] (read back in epilogue; killed by s[j][0]=0 in dots).
      oA[uu][0] = rowp[(32 ^ sws) << 2];
    }
  }
  __syncthreads();
  // Phase 2b: write E (chunks 0..31) and O (chunks 32..63), same swizzle.
#pragma unroll
  for (int uu = 0; uu < 4; uu++) {
    int unit = uu * 256 + t;
    int y = unit >> 5, xb = unit & 31;
    int sws = (y >> 1) & 15;
    float* rowp = &Sd[y * 260];
    *(float4*)&rowp[(xb ^ sws) << 2] =
        make_float4(eA[uu][0], eA[uu][1], eA[uu][2], eA[uu][3]);
    *(float4*)&rowp[((32 + xb) ^ sws) << 2] =
        make_float4(oA[uu][0], oA[uu][1], oA[uu][2], oA[uu][3]);
  }
  __syncthreads();
  // Main loop: 2 j (jg, jg+16) x 2 y per thread; 4 real dots each.
  int jg = t & 15, yg = t >> 4;
  int jm = jg & 3;                    // same for jg and jg+16
  const float4* pC0 = &Tc[jg * 17];
  const float4* pS0 = &Ts[jg * 17];
  const float4* pC1 = &Tc[(jg + 16) * 17];
  const float4* pS1 = &Ts[(jg + 16) * 17];
  // E1 half uses cos(theta+pi*j/2): jm 0:+C 1:-S 2:-C 3:+S
  // O1 half uses sin(theta+pi*j/2): jm 0:+S 1:+C 2:-S 3:-C
  const float4* p2_0 = (jm & 1) ? pS0 : pC0;
  const float4* p4_0 = (jm & 1) ? pC0 : pS0;
  const float4* p2_1 = (jm & 1) ? pS1 : pC1;
  const float4* p4_1 = (jm & 1) ? pC1 : pS1;
  float sa = (jm == 0 || jm == 3) ? 1.f : -1.f;
  float sb_ = (jm < 2) ? 1.f : -1.f;
  float pm = (jg & 1) ? -1.f : 1.f;   // (-1)^j, same parity for jg and jg+16
  int sw = yg & 15;                   // (y>>1)&15 for y=2yg, 2yg+1
  const float* row0 = &Sd[(2 * yg) * 260];
  const float* row1 = &Sd[(2 * yg + 1) * 260];
  float d1[2][2], d2[2][2], d3[2][2], d4[2][2];
#pragma unroll
  for (int a = 0; a < 2; a++)
#pragma unroll
    for (int b = 0; b < 2; b++) { d1[a][b] = 0.f; d2[a][b] = 0.f; d3[a][b] = 0.f; d4[a][b] = 0.f; }
#define DOT4(a, b) (a.x * b.x + a.y * b.y + a.z * b.z + a.w * b.w)
#pragma unroll 4
  for (int xb = 0; xb < 16; xb++) {
    int off = (xb ^ sw) << 2;
    float4 e0y0 = *(const float4*)&row0[off];
    float4 e1y0 = *(const float4*)&row0[off + 64];
    float4 o0y0 = *(const float4*)&row0[off + 128];
    float4 o1y0 = *(const float4*)&row0[off + 192];
    float4 e0y1 = *(const float4*)&row1[off];
    float4 e1y1 = *(const float4*)&row1[off + 64];
    float4 o0y1 = *(const float4*)&row1[off + 128];
    float4 o1y1 = *(const float4*)&row1[off + 192];
    float4 c0 = pC0[xb], s0 = pS0[xb];
    float4 t20 = p2_0[xb], t40 = p4_0[xb];
    float4 c1 = pC1[xb], s1 = pS1[xb];
    float4 t21 = p2_1[xb], t41 = p4_1[xb];
    d1[0][0] += DOT4(e0y0, c0);  d1[0][1] += DOT4(e0y1, c0);
    d1[1][0] += DOT4(e0y0, c1);  d1[1][1] += DOT4(e0y1, c1);
    d2[0][0] += DOT4(e1y0, t20); d2[0][1] += DOT4(e1y1, t20);
    d2[1][0] += DOT4(e1y0, t21); d2[1][1] += DOT4(e1y1, t21);
    d3[0][0] += DOT4(o0y0, s0);  d3[0][1] += DOT4(o0y1, s0);
    d3[1][0] += DOT4(o0y0, s1);  d3[1][1] += DOT4(o0y1, s1);
    d4[0][0] += DOT4(o1y0, t40); d4[0][1] += DOT4(o1y1, t40);
    d4[1][0] += DOT4(o1y0, t41); d4[1][1] += DOT4(o1y1, t41);
  }
#undef DOT4
  float u128_0 = row0[128 + 4 * sw];  // slot 128 (chunk 32^sw, elem 0)
  float u128_1 = row1[128 + 4 * sw];
#pragma unroll
  for (int jj = 0; jj < 2; jj++) {
    int j = jg + 16 * jj;
#pragma unroll
    for (int ky = 0; ky < 2; ky++) {
      int y = chunk * 32 + yg * 2 + ky;
      float u128 = ky ? u128_1 : u128_0;
      float re = d1[jj][ky] + sa * d2[jj][ky] + pm * u128;
      float im = -(d3[jj][ky] + sb_ * d4[jj][ky]);
      R[((size_t)plane * 128 + y) * 32 + j] = make_float2(re, im);
    }
  }
}

// y-DFT with row pairing (r, r+96): factor i^y. Output plane-major dst[plane][i64*32+j].
__global__ __launch_bounds__(256) void fwd_cols(const float2* __restrict__ Rg,
                                                float2* __restrict__ dst,
                                                const float* __restrict__ ws) {
  int plane = blockIdx.x;
  __shared__ float4 Rs4[2048];   // [y=128][j=32] float2 = 2048 float4 (32 KB)
  __shared__ float4 TPs[2048];   // [p][y2] (32 KB)
  float2* Rs = (float2*)Rs4;
  int t = threadIdx.x;
  const float4* in4 = (const float4*)(Rg + (size_t)plane * 4096);
#pragma unroll
  for (int k = 0; k < 8; k++) Rs4[t + 256 * k] = in4[t + 256 * k];
  const float4* gTP = (const float4*)(ws + OFF_TP);
#pragma unroll
  for (int k = 0; k < 8; k++) TPs[t + 256 * k] = gTP[t + 256 * k];
  __syncthreads();
  int j = t & 31, pg = t >> 5;
  float Are[4], Aim[4], Bre[4], Bim[4];
#pragma unroll
  for (int m = 0; m < 4; m++) { Are[m] = Aim[m] = Bre[m] = Bim[m] = 0.f; }
  for (int it = 0; it < 32; it++) {
#pragma unroll
    for (int h = 0; h < 2; h++) {
      int y2 = 2 * it + h;
      float sg = (h == 0) ? 1.f : -1.f;  // (-1)^y2
      float2 r0 = Rs[(2 * y2) * 32 + j];
      float2 r1 = Rs[(2 * y2 + 1) * 32 + j];
#pragma unroll
      for (int m = 0; m < 4; m++) {
        int p = pg + 8 * m;
        float4 tw = TPs[p * 64 + y2];
        float P0 = r0.x * tw.x + r0.y * tw.y;
        float Q0 = r0.y * tw.x - r0.x * tw.y;
        float P1 = r1.x * tw.z + r1.y * tw.w;
        float Q1 = r1.y * tw.z - r1.x * tw.w;
        Are[m] += P0 + P1;
        Aim[m] += Q0 + Q1;
        Bre[m] += sg * (P0 - Q1);   // i^y fold: even +sg*(P,Q); odd +sg*(-Q,P)
        Bim[m] += sg * (Q0 + P1);
      }
    }
  }
  size_t ob = (size_t)plane * 2048;
#pragma unroll
  for (int m = 0; m < 4; m++) {
    int p = pg + 8 * m;
    dst[ob + p * 32 + j] = make_float2(Are[m], Aim[m]);
    dst[ob + (32 + p) * 32 + j] = make_float2(Bre[m], Bim[m]);
  }
}

// Wk[mode][c][o] = Km[c][mode] * (w1|w2)[c][o][r][j]
__global__ __launch_bounds__(256) void wk_build(const float* __restrict__ w1r,
                                                const float* __restrict__ w1i,
                                                const float* __restrict__ w2r,
                                                const float* __restrict__ w2i,
                                                float2* __restrict__ wk,
                                                const float2* __restrict__ km) {
  int e0 = blockIdx.x * 256 + threadIdx.x;
#pragma unroll
  for (int k = 0; k < 4; k++) {
    int e = e0 + k * 524288;
    int o = e & 31, c = (e >> 5) & 31, j = (e >> 10) & 31, i64 = e >> 15;
    int r = (i64 < 32) ? i64 : i64 - 32;
    const float* wr = (i64 < 32) ? w1r : w2r;
    const float* wi = (i64 < 32) ? w1i : w2i;
    int widx = ((c * 32 + o) * 32 + r) * 32 + j;
    float wrv = wr[widx], wiv = wi[widx];
    float2 kv = km[(size_t)c * 2048 + i64 * 32 + j];
    wk[e] = make_float2(kv.x * wrv - kv.y * wiv, kv.x * wiv + kv.y * wrv);
  }
}

// Per-mode channel mixing on plane-major xm; XCD-swizzled gather/scatter.
__global__ __launch_bounds__(256) void mix_modes(float2* __restrict__ xm,
                                                 const float2* __restrict__ wk) {
  int bid = blockIdx.x;
  int mode = (bid & 7) * 256 + (bid >> 3);
  __shared__ float4 Xs4[512], Ws4[512];
  float2* Xs = (float2*)Xs4;
  float2* Wsl = (float2*)Ws4;
  int t = threadIdx.x;
#pragma unroll
  for (int k = 0; k < 4; k++) {
    int p = t + 256 * k;
    Xs[p] = xm[(size_t)p * 2048 + mode];
  }
  const float4* wk4 = (const float4*)(wk + (size_t)mode * 1024);
#pragma unroll
  for (int k = 0; k < 2; k++) Ws4[t + 256 * k] = wk4[t + 256 * k];
  __syncthreads();
  int o = t & 31, bg = t >> 5;
  float orr[4], oii[4];
#pragma unroll
  for (int m = 0; m < 4; m++) { orr[m] = 0.f; oii[m] = 0.f; }
  for (int c2 = 0; c2 < 16; c2++) {
    float2 w0 = Wsl[(2 * c2) * 32 + o];
    float2 w1 = Wsl[(2 * c2 + 1) * 32 + o];
#pragma unroll
    for (int m = 0; m < 4; m++) {
      float4 xv = *(const float4*)&Xs[(bg * 4 + m) * 32 + 2 * c2];
      orr[m] += xv.x * w0.x - xv.y * w0.y + xv.z * w1.x - xv.w * w1.y;
      oii[m] += xv.x * w0.y + xv.y * w0.x + xv.z * w1.y + xv.w * w1.x;
    }
  }
#pragma unroll
  for (int m = 0; m < 4; m++)
    xm[(size_t)((bg * 4 + m) * 32 + o) * 2048 + mode] = make_float2(orr[m], oii[m]);
}

// Inverse y-DFT with pairing: G[y] = sum_p (A_p + (-i)^y B_p) e^{+i theta_py}; scaling folded.
__global__ __launch_bounds__(256) void inv_rows(const float2* __restrict__ om,
                                                float2* __restrict__ G,
                                                const float* __restrict__ ws) {
  int plane = blockIdx.x;
  __shared__ float4 Os4[1024];   // [i64][j] float2 (2048 float2)
  __shared__ float4 TPs[2048];
  float2* Os = (float2*)Os4;
  int t = threadIdx.x;
  const float4* in4 = (const float4*)(om + (size_t)plane * 2048);
#pragma unroll
  for (int k = 0; k < 4; k++) Os4[t + 256 * k] = in4[t + 256 * k];
  const float4* gTP = (const float4*)(ws + OFF_TP);
#pragma unroll
  for (int k = 0; k < 8; k++) TPs[t + 256 * k] = gTP[t + 256 * k];
  __syncthreads();
  int j = t & 31, yg = t >> 5;
  float gr[16], gi[16];
#pragma unroll
  for (int k = 0; k < 16; k++) { gr[k] = 0.f; gi[k] = 0.f; }
  for (int p = 0; p < 32; p++) {
    float2 A = Os[p * 32 + j];
    float2 B = Os[(32 + p) * 32 + j];
#pragma unroll
    for (int mp = 0; mp < 8; mp++) {
      int y2 = yg * 8 + mp;
      float4 tw = TPs[p * 64 + y2];
      float sg = ((mp & 1) == 0) ? 1.f : -1.f;  // (-1)^y2
      float Sr = A.x + sg * B.x, Si = A.y + sg * B.y;          // y even
      gr[2 * mp]     += Sr * tw.x - Si * tw.y;
      gi[2 * mp]     += Sr * tw.y + Si * tw.x;
      float Tr = A.x + sg * B.y, Ti = A.y - sg * B.x;          // y odd: +sg*(-i)B
      gr[2 * mp + 1] += Tr * tw.z - Ti * tw.w;
      gi[2 * mp + 1] += Tr * tw.w + Ti * tw.z;
    }
  }
  const float inv = 1.0f / 32768.0f;
  size_t gb = (size_t)plane * 128;
#pragma unroll
  for (int mm = 0; mm < 16; mm++) {
    int y = yg * 16 + mm;
    float sr = (j == 0) ? gr[mm] * inv : 2.f * inv * gr[mm];
    float si = (j == 0) ? 0.f : 2.f * inv * gi[mm];
    G[(gb + y) * 32 + j] = make_float2(sr, si);
  }
}

// Inverse x-DFT, double-folded: out real, 32 modes.
//   C[x]=sum_j gr c[jx], S[x]=sum_j gi s[jx]; split by j parity (Ce,Co,Se,So), x<64:
//   out[x]      = (Ce+Co) - (Se+So)
//   out[128-x]  = (Ce-Co) - (So-Se)
//   out[128+x]  = (Ce-Co) + (So-Se)
//   out[256-x]  = (Ce+Co) + (Se+So)
//   out[64]/out[192] from alternating-sign sums (theta=pi*j/2).
__global__ __launch_bounds__(256) void inv_cols(const float2* __restrict__ G,
                                                float* __restrict__ out,
                                                const float* __restrict__ ws) {
  int plane = blockIdx.x >> 2, chunk = blockIdx.x & 3;
  __shared__ float2 Gs[32 * 33];       // padded [yl][33]
  __shared__ float4 Tc[544], Ts[544];  // [j][17] padded
  int t = threadIdx.x;
  const float2* in = G + (size_t)plane * 4096 + (size_t)chunk * 1024;
#pragma unroll
  for (int k = 0; k < 4; k++) {
    int idx = t + 256 * k;
    Gs[(idx >> 5) * 33 + (idx & 31)] = in[idx];
  }
  const float4* gTc = (const float4*)(ws + OFF_TQC);
  const float4* gTs = (const float4*)(ws + OFF_TQS);
#pragma unroll
  for (int k = 0; k < 2; k++) {
    int idx = t + 256 * k;
    Tc[(idx >> 4) * 17 + (idx & 15)] = gTc[idx];
    Ts[(idx >> 4) * 17 + (idx & 15)] = gTs[idx];
  }
  __syncthreads();
  int xi = t & 15, yg = t >> 4;   // x' = 4*xi+m in [0,64); y = 2*yg, 2*yg+1
  float4 Ce[2], Co[2], Se[2], So[2];
  float c64[2], s64[2];
#pragma unroll
  for (int ky = 0; ky < 2; ky++) {
    Ce[ky] = make_float4(0.f, 0.f, 0.f, 0.f);
    Co[ky] = make_float4(0.f, 0.f, 0.f, 0.f);
    Se[ky] = make_float4(0.f, 0.f, 0.f, 0.f);
    So[ky] = make_float4(0.f, 0.f, 0.f, 0.f);
    c64[ky] = 0.f; s64[ky] = 0.f;
  }
#define FMA4(acc, s, v) do { acc.x += (s) * (v).x; acc.y += (s) * (v).y; \
                             acc.z += (s) * (v).z; acc.w += (s) * (v).w; } while (0)
#pragma unroll 4
  for (int jh = 0; jh < 16; jh++) {
    float4 ce = Tc[(2 * jh) * 17 + xi],     se = Ts[(2 * jh) * 17 + xi];
    float4 co = Tc[(2 * jh + 1) * 17 + xi], so = Ts[(2 * jh + 1) * 17 + xi];
    float sgn = (jh & 1) ? -1.f : 1.f;      // cos(pi*jh), for x=64 boundary sums
#pragma unroll
    for (int ky = 0; ky < 2; ky++) {
      float2 ge = Gs[(yg * 2 + ky) * 33 + 2 * jh];
      float2 go = Gs[(yg * 2 + ky) * 33 + 2 * jh + 1];
      FMA4(Ce[ky], ge.x, ce);
      FMA4(Se[ky], ge.y, se);
      FMA4(Co[ky], go.x, co);
      FMA4(So[ky], go.y, so);
      c64[ky] += sgn * ge.x;   // sum_j gr*cos(pi*j/2) (even j only nonzero)
      s64[ky] += sgn * go.y;   // sum_j gi*sin(pi*j/2) (odd j only nonzero)
    }
  }
#undef FMA4
  float* outp = out + (size_t)plane * PLANE + (size_t)chunk * 32 * Wn;
#pragma unroll
  for (int ky = 0; ky < 2; ky++) {
    int y = yg * 2 + ky;
    float* ro = outp + y * Wn;
    float4 C  = make_float4(Ce[ky].x + Co[ky].x, Ce[ky].y + Co[ky].y,
                            Ce[ky].z + Co[ky].z, Ce[ky].w + Co[ky].w);
    float4 Cm = make_float4(Ce[ky].x - Co[ky].x, Ce[ky].y - Co[ky].y,
                            Ce[ky].z - Co[ky].z, Ce[ky].w - Co[ky].w);
    float4 S  = make_float4(Se[ky].x + So[ky].x, Se[ky].y + So[ky].y,
                            Se[ky].z + So[ky].z, Se[ky].w + So[ky].w);
    float4 Sm = make_float4(So[ky].x - Se[ky].x, So[ky].y - Se[ky].y,
                            So[ky].z - Se[ky].z, So[ky].w - Se[ky].w);
    // forward aligned quarters
    *(float4*)(ro + 4 * xi) =
        make_float4(C.x - S.x, C.y - S.y, C.z - S.z, C.w - S.w);          // out[x]
    *(float4*)(ro + 128 + 4 * xi) =
        make_float4(Cm.x + Sm.x, Cm.y + Sm.y, Cm.z + Sm.z, Cm.w + Sm.w);  // out[128+x]
    // mirrored quarters (reversed, scalar stores)
    int mb = 128 - 4 * xi;
    ro[mb]     = Cm.x - Sm.x;   // out[128-x], m=0
    ro[mb - 1] = Cm.y - Sm.y;
    ro[mb - 2] = Cm.z - Sm.z;
    ro[mb - 3] = Cm.w - Sm.w;
    int nb = 256 - 4 * xi;
    if (xi) ro[nb] = C.x + S.x; // out[256-x], m=0 (skip x=0 -> idx 256)
    ro[nb - 1] = C.y + S.y;
    ro[nb - 2] = C.z + S.z;
    ro[nb - 3] = C.w + S.w;
    if (xi == 0) {
      ro[64]  = c64[ky] - s64[ky];
      ro[192] = c64[ky] + s64[ky];
    }
  }
}

extern "C" void kernel_launch(void* const* d_in, const int* in_sizes, int n_in,
                              void* d_out, int out_size, void* d_ws, size_t ws_size,
                              hipStream_t stream) {
  (void)in_sizes; (void)n_in; (void)out_size; (void)ws_size;
  const float* x   = (const float*)d_in[0];
  const float* kk  = (const float*)d_in[1];
  const float* w1r = (const float*)d_in[2];
  const float* w1i = (const float*)d_in[3];
  const float* w2r = (const float*)d_in[4];
  const float* w2i = (const float*)d_in[5];
  float*  ws   = (float*)d_ws;
  float*  out  = (float*)d_out;
  float2* km2  = (float2*)(ws + OFF_KM);
  float2* xm2  = (float2*)(ws + OFF_XM);
  float2* bx   = (float2*)(ws + OFF_B);   // R -> WK -> G'
  float2* rk   = (float2*)(ws + OFF_RK);

  build_tables<<<8, 256, 0, stream>>>(ws);
  fwd_rows<<<4096, 256, 0, stream>>>(x, bx, ws);
  fwd_rows<<<128, 256, 0, stream>>>(kk, rk, ws);
  fwd_cols<<<1024, 256, 0, stream>>>(bx, xm2, ws);
  fwd_cols<<<32, 256, 0, stream>>>(rk, km2, ws);
  wk_build<<<2048, 256, 0, stream>>>(w1r, w1i, w2r, w2i, bx, km2);
  mix_modes<<<2048, 256, 0, stream>>>(xm2, bx);
  inv_rows<<<1024, 256, 0, stream>>>(xm2, bx, ws);
  inv_cols<<<4096, 256, 0, stream>>>(bx, out, ws);
}

// Round 4
// 417.864 us; speedup vs baseline: 1.0716x; 1.0178x over previous
//
#include <hip/hip_runtime.h>
#include <math.h>

#define Hn 128
#define Wn 256
#define PLANE (Hn*Wn)

// Workspace layout (float offsets)
#define OFF_TQC 0u        // [j<32][xi<16] float4: cos(2pi*j*(xi*4+m)/256), x<64 quarter
#define OFF_TQS 2048u     // sin
#define OFF_TP  4096u     // [p<32][y2<64] float4: (c,s) at y=2y2 and y=2y2+1, theta=2pi*p*y/128
#define OFF_KM  16384u    // [c=32][mode=2048] float2 (plane-major spectrum of k)
#define OFF_XM  147456u   // [plane=1024][mode=2048] float2
#define OFF_B   4341760u  // time-shared: R [1024][128][32] f2 -> WK [mode][c][o] f2 -> G' [1024][128][32] f2
#define OFF_RK  12730368u // Rk [32][128][32] float2
// total 12992512 floats = 49.6 MiB

__global__ __launch_bounds__(256) void build_tables(float* __restrict__ ws) {
  int tid = blockIdx.x * 256 + threadIdx.x; // 2048 threads
  const double PI2 = 6.283185307179586476925286766559;
  if (tid < 512) {
    int j = tid >> 4, xi = tid & 15;
    float cc[4], ss[4];
#pragma unroll
    for (int m = 0; m < 4; m++) {
      int x = xi * 4 + m;
      double ang = PI2 * (double)((j * x) & 255) / 256.0;
      cc[m] = (float)cos(ang); ss[m] = (float)sin(ang);
    }
    ((float4*)(ws + OFF_TQC))[tid] = make_float4(cc[0], cc[1], cc[2], cc[3]);
    ((float4*)(ws + OFF_TQS))[tid] = make_float4(ss[0], ss[1], ss[2], ss[3]);
  }
  if (tid < 2048) {
    int p = tid >> 6, y2 = tid & 63;
    double a0 = PI2 * (double)((p * (2 * y2)) & 127) / 128.0;
    double a1 = PI2 * (double)((p * (2 * y2 + 1)) & 127) / 128.0;
    ((float4*)(ws + OFF_TP))[tid] =
        make_float4((float)cos(a0), (float)sin(a0), (float)cos(a1), (float)sin(a1));
  }
}

// x-DFT, double-folded: R[plane][y][j] = sum_x u[y,x] e^{-2pi i j x/256}, j<32.
// Fold 1 (x<->256-x, u real) then fold 2 (x<->128-x):
//   EP[x]=a+c, EM[x]=a-c, OP[x]=b+d, OM[x]=b-d  (x in 1..63)
//   with a=u[x]+u[256-x], b=u[x]-u[256-x], c=u[128-x]+u[128+x], d=u[128-x]-u[128+x].
//   Re[j even] = sum EP[x]cos + E0 + sgE*E64 + u128      (sgE=(-1)^(j/2))
//   Re[j odd]  = sum EM[x]cos + E0 - u128
//   Im[j even] = -sum OM[x]sin
//   Im[j odd]  = -sum OP[x]sin - sgO*O64                  (sgO=(-1)^((j-1)/2))
// E0 absorbed into slot 0 of EP/EM (cos(0)=1); dots span exactly the 64-wide
// quarter tables. Signs identical for jg and jg+16.
#define RS 276  // row stride in floats; 276 % 32 == 20 spreads wave row-groups
__global__ __launch_bounds__(256, 3) void fwd_rows(const float* __restrict__ src,
                                                   float2* __restrict__ R,
                                                   const float* __restrict__ ws) {
  int plane = blockIdx.x >> 2, chunk = blockIdx.x & 3;
  // Per row (stride RS): raw u staged at slots [0..255] (16B-chunk XOR swizzle
  // c -> c^sws, sws=(y>>1)&15), then folded in place:
  //   EP @ +0 (slots 0..63), specials E64/u128/O64 @ 64/65/66,
  //   EM @ +68, OM @ +136, OP @ +204. All region bases 16B-aligned.
  __shared__ __align__(16) float Sd[32 * RS];
  __shared__ float4 Tc[544], Ts[544];  // [j][17] padded
  int t = threadIdx.x;
  const float4* src4 = (const float4*)src;
  size_t sb = (size_t)plane * 8192 + (size_t)chunk * 2048;
  // Phase 1: stage raw u tile (swizzled chunks).
#pragma unroll
  for (int k = 0; k < 8; k++) {
    int idx = t + 256 * k;           // 2048 float4 = 32 y x 64 chunks
    int row = idx >> 6, c4 = idx & 63;
    int sws = (row >> 1) & 15;
    *(float4*)&Sd[row * RS + ((c4 ^ sws) << 2)] = src4[sb + idx];
  }
  const float4* gTc = (const float4*)(ws + OFF_TQC);
  const float4* gTs = (const float4*)(ws + OFF_TQS);
#pragma unroll
  for (int k = 0; k < 2; k++) {
    int idx = t + 256 * k;
    Tc[(idx >> 4) * 17 + (idx & 15)] = gTc[idx];
    Ts[(idx >> 4) * 17 + (idx & 15)] = gTs[idx];
  }
  __syncthreads();
  // Phase 2a: 512 units (y<32, xq<16), 2 per thread; read+fold into registers.
  float EPv[2][4], EMv[2][4], OPv[2][4], OMv[2][4];
  float spE64[2], spU128[2], spO64[2];
#pragma unroll
  for (int uu = 0; uu < 2; uu++) {
    int unit = uu * 256 + t;
    int y = unit >> 4, xq = unit & 15;
    int sws = (y >> 1) & 15;
    const float* rowp = &Sd[y * RS];
    float4 A0 = *(const float4*)&rowp[(xq ^ sws) << 2];          // u[4xq+k]
    float4 A2 = *(const float4*)&rowp[((32 + xq) ^ sws) << 2];   // u[128+4xq+k]
    float Av0[4] = {A0.x, A0.y, A0.z, A0.w};
    float Av2[4] = {A2.x, A2.y, A2.z, A2.w};
    float M1[4], M2[4];
#pragma unroll
    for (int kk = 0; kk < 4; kk++) {
      int s1 = 128 - 4 * xq - kk;            // in [65..128]
      M1[kk] = rowp[(((s1 >> 2) ^ sws) << 2) + (s1 & 3)];
      int s2 = 256 - 4 * xq - kk;            // in [193..256]
      int s2c = (s2 > 255) ? 255 : s2;       // clamp; only (xq=0,k=0), overridden
      M2[kk] = rowp[(((s2c >> 2) ^ sws) << 2) + (s2c & 3)];
    }
#pragma unroll
    for (int kk = 0; kk < 4; kk++) {
      float a = Av0[kk] + M2[kk], b = Av0[kk] - M2[kk];
      float c = M1[kk] + Av2[kk], d = M1[kk] - Av2[kk];
      EPv[uu][kk] = a + c;  EMv[uu][kk] = a - c;
      OPv[uu][kk] = b + d;  OMv[uu][kk] = b - d;
    }
    spE64[uu] = 0.f; spU128[uu] = 0.f; spO64[uu] = 0.f;
    if (xq == 0) {
      EPv[uu][0] = Av0[0];  EMv[uu][0] = Av0[0];   // E0 = u[0], coeff cos(0)=1
      OPv[uu][0] = 0.f;     OMv[uu][0] = 0.f;      // sin(0)=0
      float u64v  = rowp[((16 ^ sws) << 2)];        // u[64]
      float u192v = rowp[((48 ^ sws) << 2)];        // u[192]
      spE64[uu]  = u64v + u192v;
      spO64[uu]  = u64v - u192v;
      spU128[uu] = Av2[0];                          // u[128]
    }
  }
  __syncthreads();
  // Phase 2b: write folded arrays (chunk-swizzled) + specials (unswizzled).
#pragma unroll
  for (int uu = 0; uu < 2; uu++) {
    int unit = uu * 256 + t;
    int y = unit >> 4, xq = unit & 15;
    int sws = (y >> 1) & 15;
    float* rowp = &Sd[y * RS];
    int off = (xq ^ sws) << 2;
    *(float4*)&rowp[off]       = make_float4(EPv[uu][0], EPv[uu][1], EPv[uu][2], EPv[uu][3]);
    *(float4*)&rowp[68 + off]  = make_float4(EMv[uu][0], EMv[uu][1], EMv[uu][2], EMv[uu][3]);
    *(float4*)&rowp[136 + off] = make_float4(OMv[uu][0], OMv[uu][1], OMv[uu][2], OMv[uu][3]);
    *(float4*)&rowp[204 + off] = make_float4(OPv[uu][0], OPv[uu][1], OPv[uu][2], OPv[uu][3]);
    if (xq == 0) {
      rowp[64] = spE64[uu];
      rowp[65] = spU128[uu];
      rowp[66] = spO64[uu];
    }
  }
  __syncthreads();
  // Main loop: 2 j (jg, jg+16; same parity) x 2 y per thread; 64-long dots.
  int jg = t & 15, yg = t >> 4;
  int jodd = jg & 1;
  int aC = jodd ? 68 : 0;     // EM : EP
  int aS = jodd ? 204 : 136;  // OP : OM
  const float4* pC0 = &Tc[jg * 17];
  const float4* pS0 = &Ts[jg * 17];
  const float4* pC1 = &Tc[(jg + 16) * 17];
  const float4* pS1 = &Ts[(jg + 16) * 17];
  float sgE = jodd ? 0.f : (((jg >> 1) & 1) ? -1.f : 1.f);       // cos(pi*j/2), even j
  float sgO = jodd ? ((((jg - 1) >> 1) & 1) ? -1.f : 1.f) : 0.f; // sin(pi*j/2), odd j
  float pm = jodd ? -1.f : 1.f;                                  // (-1)^j
  int sw = yg;                        // (y>>1)&15 for y=2yg, 2yg+1
  const float* row0 = &Sd[(2 * yg) * RS];
  const float* row1 = &Sd[(2 * yg + 1) * RS];
  float dc[2][2], dsn[2][2];
#pragma unroll
  for (int a = 0; a < 2; a++)
#pragma unroll
    for (int b = 0; b < 2; b++) { dc[a][b] = 0.f; dsn[a][b] = 0.f; }
#define DOT4(a, b) (a.x * b.x + a.y * b.y + a.z * b.z + a.w * b.w)
#pragma unroll 4
  for (int xb = 0; xb < 16; xb++) {
    int off = (xb ^ sw) << 2;
    float4 eY0 = *(const float4*)&row0[aC + off];
    float4 eY1 = *(const float4*)&row1[aC + off];
    float4 oY0 = *(const float4*)&row0[aS + off];
    float4 oY1 = *(const float4*)&row1[aS + off];
    float4 c0 = pC0[xb], s0 = pS0[xb];
    float4 c1 = pC1[xb], s1 = pS1[xb];
    dc[0][0] += DOT4(eY0, c0);  dc[0][1] += DOT4(eY1, c0);
    dc[1][0] += DOT4(eY0, c1);  dc[1][1] += DOT4(eY1, c1);
    dsn[0][0] += DOT4(oY0, s0); dsn[0][1] += DOT4(oY1, s0);
    dsn[1][0] += DOT4(oY0, s1); dsn[1][1] += DOT4(oY1, s1);
  }
#undef DOT4
  float E64_0 = row0[64], u128_0 = row0[65], O64_0 = row0[66];
  float E64_1 = row1[64], u128_1 = row1[65], O64_1 = row1[66];
#pragma unroll
  for (int jj = 0; jj < 2; jj++) {
    int j = jg + 16 * jj;
#pragma unroll
    for (int ky = 0; ky < 2; ky++) {
      int y = chunk * 32 + yg * 2 + ky;
      float E64 = ky ? E64_1 : E64_0;
      float u128 = ky ? u128_1 : u128_0;
      float O64 = ky ? O64_1 : O64_0;
      float re = dc[jj][ky] + sgE * E64 + pm * u128;
      float im = -dsn[jj][ky] - sgO * O64;
      R[((size_t)plane * 128 + y) * 32 + j] = make_float2(re, im);
    }
  }
}
#undef RS

// y-DFT with row pairing (r, r+96): factor i^y. Output plane-major dst[plane][i64*32+j].
__global__ __launch_bounds__(256) void fwd_cols(const float2* __restrict__ Rg,
                                                float2* __restrict__ dst,
                                                const float* __restrict__ ws) {
  int plane = blockIdx.x;
  __shared__ float4 Rs4[2048];   // [y=128][j=32] float2 = 2048 float4 (32 KB)
  __shared__ float4 TPs[2048];   // [p][y2] (32 KB)
  float2* Rs = (float2*)Rs4;
  int t = threadIdx.x;
  const float4* in4 = (const float4*)(Rg + (size_t)plane * 4096);
#pragma unroll
  for (int k = 0; k < 8; k++) Rs4[t + 256 * k] = in4[t + 256 * k];
  const float4* gTP = (const float4*)(ws + OFF_TP);
#pragma unroll
  for (int k = 0; k < 8; k++) TPs[t + 256 * k] = gTP[t + 256 * k];
  __syncthreads();
  int j = t & 31, pg = t >> 5;
  float Are[4], Aim[4], Bre[4], Bim[4];
#pragma unroll
  for (int m = 0; m < 4; m++) { Are[m] = Aim[m] = Bre[m] = Bim[m] = 0.f; }
  for (int it = 0; it < 32; it++) {
#pragma unroll
    for (int h = 0; h < 2; h++) {
      int y2 = 2 * it + h;
      float sg = (h == 0) ? 1.f : -1.f;  // (-1)^y2
      float2 r0 = Rs[(2 * y2) * 32 + j];
      float2 r1 = Rs[(2 * y2 + 1) * 32 + j];
#pragma unroll
      for (int m = 0; m < 4; m++) {
        int p = pg + 8 * m;
        float4 tw = TPs[p * 64 + y2];
        float P0 = r0.x * tw.x + r0.y * tw.y;
        float Q0 = r0.y * tw.x - r0.x * tw.y;
        float P1 = r1.x * tw.z + r1.y * tw.w;
        float Q1 = r1.y * tw.z - r1.x * tw.w;
        Are[m] += P0 + P1;
        Aim[m] += Q0 + Q1;
        Bre[m] += sg * (P0 - Q1);   // i^y fold: even +sg*(P,Q); odd +sg*(-Q,P)
        Bim[m] += sg * (Q0 + P1);
      }
    }
  }
  size_t ob = (size_t)plane * 2048;
#pragma unroll
  for (int m = 0; m < 4; m++) {
    int p = pg + 8 * m;
    dst[ob + p * 32 + j] = make_float2(Are[m], Aim[m]);
    dst[ob + (32 + p) * 32 + j] = make_float2(Bre[m], Bim[m]);
  }
}

// Wk[mode][c][o] = Km[c][mode] * (w1|w2)[c][o][r][j]
__global__ __launch_bounds__(256) void wk_build(const float* __restrict__ w1r,
                                                const float* __restrict__ w1i,
                                                const float* __restrict__ w2r,
                                                const float* __restrict__ w2i,
                                                float2* __restrict__ wk,
                                                const float2* __restrict__ km) {
  int e0 = blockIdx.x * 256 + threadIdx.x;
#pragma unroll
  for (int k = 0; k < 4; k++) {
    int e = e0 + k * 524288;
    int o = e & 31, c = (e >> 5) & 31, j = (e >> 10) & 31, i64 = e >> 15;
    int r = (i64 < 32) ? i64 : i64 - 32;
    const float* wr = (i64 < 32) ? w1r : w2r;
    const float* wi = (i64 < 32) ? w1i : w2i;
    int widx = ((c * 32 + o) * 32 + r) * 32 + j;
    float wrv = wr[widx], wiv = wi[widx];
    float2 kv = km[(size_t)c * 2048 + i64 * 32 + j];
    wk[e] = make_float2(kv.x * wrv - kv.y * wiv, kv.x * wiv + kv.y * wrv);
  }
}

// Per-mode channel mixing on plane-major xm; XCD-swizzled gather/scatter.
__global__ __launch_bounds__(256) void mix_modes(float2* __restrict__ xm,
                                                 const float2* __restrict__ wk) {
  int bid = blockIdx.x;
  int mode = (bid & 7) * 256 + (bid >> 3);
  __shared__ float4 Xs4[512], Ws4[512];
  float2* Xs = (float2*)Xs4;
  float2* Wsl = (float2*)Ws4;
  int t = threadIdx.x;
#pragma unroll
  for (int k = 0; k < 4; k++) {
    int p = t + 256 * k;
    Xs[p] = xm[(size_t)p * 2048 + mode];
  }
  const float4* wk4 = (const float4*)(wk + (size_t)mode * 1024);
#pragma unroll
  for (int k = 0; k < 2; k++) Ws4[t + 256 * k] = wk4[t + 256 * k];
  __syncthreads();
  int o = t & 31, bg = t >> 5;
  float orr[4], oii[4];
#pragma unroll
  for (int m = 0; m < 4; m++) { orr[m] = 0.f; oii[m] = 0.f; }
  for (int c2 = 0; c2 < 16; c2++) {
    float2 w0 = Wsl[(2 * c2) * 32 + o];
    float2 w1 = Wsl[(2 * c2 + 1) * 32 + o];
#pragma unroll
    for (int m = 0; m < 4; m++) {
      float4 xv = *(const float4*)&Xs[(bg * 4 + m) * 32 + 2 * c2];
      orr[m] += xv.x * w0.x - xv.y * w0.y + xv.z * w1.x - xv.w * w1.y;
      oii[m] += xv.x * w0.y + xv.y * w0.x + xv.z * w1.y + xv.w * w1.x;
    }
  }
#pragma unroll
  for (int m = 0; m < 4; m++)
    xm[(size_t)((bg * 4 + m) * 32 + o) * 2048 + mode] = make_float2(orr[m], oii[m]);
}

// Inverse y-DFT with pairing: G[y] = sum_p (A_p + (-i)^y B_p) e^{+i theta_py}; scaling folded.
__global__ __launch_bounds__(256) void inv_rows(const float2* __restrict__ om,
                                                float2* __restrict__ G,
                                                const float* __restrict__ ws) {
  int plane = blockIdx.x;
  __shared__ float4 Os4[1024];   // [i64][j] float2 (2048 float2)
  __shared__ float4 TPs[2048];
  float2* Os = (float2*)Os4;
  int t = threadIdx.x;
  const float4* in4 = (const float4*)(om + (size_t)plane * 2048);
#pragma unroll
  for (int k = 0; k < 4; k++) Os4[t + 256 * k] = in4[t + 256 * k];
  const float4* gTP = (const float4*)(ws + OFF_TP);
#pragma unroll
  for (int k = 0; k < 8; k++) TPs[t + 256 * k] = gTP[t + 256 * k];
  __syncthreads();
  int j = t & 31, yg = t >> 5;
  float gr[16], gi[16];
#pragma unroll
  for (int k = 0; k < 16; k++) { gr[k] = 0.f; gi[k] = 0.f; }
  for (int p = 0; p < 32; p++) {
    float2 A = Os[p * 32 + j];
    float2 B = Os[(32 + p) * 32 + j];
#pragma unroll
    for (int mp = 0; mp < 8; mp++) {
      int y2 = yg * 8 + mp;
      float4 tw = TPs[p * 64 + y2];
      float sg = ((mp & 1) == 0) ? 1.f : -1.f;  // (-1)^y2
      float Sr = A.x + sg * B.x, Si = A.y + sg * B.y;          // y even
      gr[2 * mp]     += Sr * tw.x - Si * tw.y;
      gi[2 * mp]     += Sr * tw.y + Si * tw.x;
      float Tr = A.x + sg * B.y, Ti = A.y - sg * B.x;          // y odd: +sg*(-i)B
      gr[2 * mp + 1] += Tr * tw.z - Ti * tw.w;
      gi[2 * mp + 1] += Tr * tw.w + Ti * tw.z;
    }
  }
  const float inv = 1.0f / 32768.0f;
  size_t gb = (size_t)plane * 128;
#pragma unroll
  for (int mm = 0; mm < 16; mm++) {
    int y = yg * 16 + mm;
    float sr = (j == 0) ? gr[mm] * inv : 2.f * inv * gr[mm];
    float si = (j == 0) ? 0.f : 2.f * inv * gi[mm];
    G[(gb + y) * 32 + j] = make_float2(sr, si);
  }
}

// Inverse x-DFT, double-folded: out real, 32 modes.
//   C[x]=sum_j gr c[jx], S[x]=sum_j gi s[jx]; split by j parity (Ce,Co,Se,So), x<64:
//   out[x]      = (Ce+Co) - (Se+So)
//   out[128-x]  = (Ce-Co) - (So-Se)
//   out[128+x]  = (Ce-Co) + (So-Se)
//   out[256-x]  = (Ce+Co) + (Se+So)
//   out[64]/out[192] from alternating-sign sums (theta=pi*j/2).
__global__ __launch_bounds__(256) void inv_cols(const float2* __restrict__ G,
                                                float* __restrict__ out,
                                                const float* __restrict__ ws) {
  int plane = blockIdx.x >> 2, chunk = blockIdx.x & 3;
  __shared__ float2 Gs[32 * 33];       // padded [yl][33]
  __shared__ float4 Tc[544], Ts[544];  // [j][17] padded
  int t = threadIdx.x;
  const float2* in = G + (size_t)plane * 4096 + (size_t)chunk * 1024;
#pragma unroll
  for (int k = 0; k < 4; k++) {
    int idx = t + 256 * k;
    Gs[(idx >> 5) * 33 + (idx & 31)] = in[idx];
  }
  const float4* gTc = (const float4*)(ws + OFF_TQC);
  const float4* gTs = (const float4*)(ws + OFF_TQS);
#pragma unroll
  for (int k = 0; k < 2; k++) {
    int idx = t + 256 * k;
    Tc[(idx >> 4) * 17 + (idx & 15)] = gTc[idx];
    Ts[(idx >> 4) * 17 + (idx & 15)] = gTs[idx];
  }
  __syncthreads();
  int xi = t & 15, yg = t >> 4;   // x' = 4*xi+m in [0,64); y = 2*yg, 2*yg+1
  float4 Ce[2], Co[2], Se[2], So[2];
  float c64[2], s64[2];
#pragma unroll
  for (int ky = 0; ky < 2; ky++) {
    Ce[ky] = make_float4(0.f, 0.f, 0.f, 0.f);
    Co[ky] = make_float4(0.f, 0.f, 0.f, 0.f);
    Se[ky] = make_float4(0.f, 0.f, 0.f, 0.f);
    So[ky] = make_float4(0.f, 0.f, 0.f, 0.f);
    c64[ky] = 0.f; s64[ky] = 0.f;
  }
#define FMA4(acc, s, v) do { acc.x += (s) * (v).x; acc.y += (s) * (v).y; \
                             acc.z += (s) * (v).z; acc.w += (s) * (v).w; } while (0)
#pragma unroll 4
  for (int jh = 0; jh < 16; jh++) {
    float4 ce = Tc[(2 * jh) * 17 + xi],     se = Ts[(2 * jh) * 17 + xi];
    float4 co = Tc[(2 * jh + 1) * 17 + xi], so = Ts[(2 * jh + 1) * 17 + xi];
    float sgn = (jh & 1) ? -1.f : 1.f;      // cos(pi*jh), for x=64 boundary sums
#pragma unroll
    for (int ky = 0; ky < 2; ky++) {
      float2 ge = Gs[(yg * 2 + ky) * 33 + 2 * jh];
      float2 go = Gs[(yg * 2 + ky) * 33 + 2 * jh + 1];
      FMA4(Ce[ky], ge.x, ce);
      FMA4(Se[ky], ge.y, se);
      FMA4(Co[ky], go.x, co);
      FMA4(So[ky], go.y, so);
      c64[ky] += sgn * ge.x;   // sum_j gr*cos(pi*j/2) (even j only nonzero)
      s64[ky] += sgn * go.y;   // sum_j gi*sin(pi*j/2) (odd j only nonzero)
    }
  }
#undef FMA4
  float* outp = out + (size_t)plane * PLANE + (size_t)chunk * 32 * Wn;
#pragma unroll
  for (int ky = 0; ky < 2; ky++) {
    int y = yg * 2 + ky;
    float* ro = outp + y * Wn;
    float4 C  = make_float4(Ce[ky].x + Co[ky].x, Ce[ky].y + Co[ky].y,
                            Ce[ky].z + Co[ky].z, Ce[ky].w + Co[ky].w);
    float4 Cm = make_float4(Ce[ky].x - Co[ky].x, Ce[ky].y - Co[ky].y,
                            Ce[ky].z - Co[ky].z, Ce[ky].w - Co[ky].w);
    float4 S  = make_float4(Se[ky].x + So[ky].x, Se[ky].y + So[ky].y,
                            Se[ky].z + So[ky].z, Se[ky].w + So[ky].w);
    float4 Sm = make_float4(So[ky].x - Se[ky].x, So[ky].y - Se[ky].y,
                            So[ky].z - Se[ky].z, So[ky].w - Se[ky].w);
    // forward aligned quarters
    *(float4*)(ro + 4 * xi) =
        make_float4(C.x - S.x, C.y - S.y, C.z - S.z, C.w - S.w);          // out[x]
    *(float4*)(ro + 128 + 4 * xi) =
        make_float4(Cm.x + Sm.x, Cm.y + Sm.y, Cm.z + Sm.z, Cm.w + Sm.w);  // out[128+x]
    // mirrored quarters (reversed, scalar stores)
    int mb = 128 - 4 * xi;
    ro[mb]     = Cm.x - Sm.x;   // out[128-x], m=0
    ro[mb - 1] = Cm.y - Sm.y;
    ro[mb - 2] = Cm.z - Sm.z;
    ro[mb - 3] = Cm.w - Sm.w;
    int nb = 256 - 4 * xi;
    if (xi) ro[nb] = C.x + S.x; // out[256-x], m=0 (skip x=0 -> idx 256)
    ro[nb - 1] = C.y + S.y;
    ro[nb - 2] = C.z + S.z;
    ro[nb - 3] = C.w + S.w;
    if (xi == 0) {
      ro[64]  = c64[ky] - s64[ky];
      ro[192] = c64[ky] + s64[ky];
    }
  }
}

extern "C" void kernel_launch(void* const* d_in, const int* in_sizes, int n_in,
                              void* d_out, int out_size, void* d_ws, size_t ws_size,
                              hipStream_t stream) {
  (void)in_sizes; (void)n_in; (void)out_size; (void)ws_size;
  const float* x   = (const float*)d_in[0];
  const float* kk  = (const float*)d_in[1];
  const float* w1r = (const float*)d_in[2];
  const float* w1i = (const float*)d_in[3];
  const float* w2r = (const float*)d_in[4];
  const float* w2i = (const float*)d_in[5];
  float*  ws   = (float*)d_ws;
  float*  out  = (float*)d_out;
  float2* km2  = (float2*)(ws + OFF_KM);
  float2* xm2  = (float2*)(ws + OFF_XM);
  float2* bx   = (float2*)(ws + OFF_B);   // R -> WK -> G'
  float2* rk   = (float2*)(ws + OFF_RK);

  build_tables<<<8, 256, 0, stream>>>(ws);
  fwd_rows<<<4096, 256, 0, stream>>>(x, bx, ws);
  fwd_rows<<<128, 256, 0, stream>>>(kk, rk, ws);
  fwd_cols<<<1024, 256, 0, stream>>>(bx, xm2, ws);
  fwd_cols<<<32, 256, 0, stream>>>(rk, km2, ws);
  wk_build<<<2048, 256, 0, stream>>>(w1r, w1i, w2r, w2i, bx, km2);
  mix_modes<<<2048, 256, 0, stream>>>(xm2, bx);
  inv_rows<<<1024, 256, 0, stream>>>(xm2, bx, ws);
  inv_cols<<<4096, 256, 0, stream>>>(bx, out, ws);
}